// Round 15
// baseline (85.089 us; speedup 1.0000x reference)
//
#include <hip/hip_runtime.h>

// B=16, N=2048, C=128, S=25, D_AGG=128, D_OUT=128
// in: A[16,2048,2048] f32, X[16,2048,128] f32, Wa[128,128] f32, ba[128] f32,
//     Wc[256,128] f32, bc[128] f32, n_samples i32
// out: [16,2048,128] f32
//
// Pipeline (R13 structure exactly; A loads now CACHEABLE (no NT hint) to
// maximize L3 retention across graph replays — R7 measured FETCH 154MB<256MB
// even with NT; plain loads should retain more):
//   K1     : H = relu(X @ Wa + ba) -> bf16 (MFMA; inline Wa transpose)
//   K2     : agg = max over first-S neighbors of H rows (rank-scan + 32-wide
//            batched gather; batch-affine XCD mapping for H L2 locality)
//            + blocks >= 8192 prep Wc -> Wct bf16
//   K3     : out = relu([X|agg] @ Wc + bc) -> f32 + partial sumsq (MFMA)
//   K5     : out *= 1/frobnorm per batch (div_no_nan)
//
// ws: H 8MB @0, agg 8MB @8M, Wct 64K @16M, partials 1K @16M+64K

typedef __attribute__((ext_vector_type(8))) short short8;   // bf16x8 raw bits
typedef __attribute__((ext_vector_type(4))) float f32x4;
typedef __attribute__((ext_vector_type(4))) float fvec4;
typedef unsigned int uint;
typedef unsigned short ushort;

__device__ __forceinline__ ushort f2bf(float x) {           // RNE f32->bf16
    uint u = __builtin_bit_cast(uint, x);
    u += 0x7FFFu + ((u >> 16) & 1u);
    return (ushort)(u >> 16);
}
__device__ __forceinline__ float bflo(uint h) { uint v = h << 16;         return __builtin_bit_cast(float, v); }
__device__ __forceinline__ float bfhi(uint h) { uint v = h & 0xFFFF0000u; return __builtin_bit_cast(float, v); }
// popcount(mask & lanemask_lt) in 2 VALU ops (R9/R11/R13-proven)
__device__ __forceinline__ int mbcnt64(unsigned long long m) {
    return __builtin_amdgcn_mbcnt_hi((uint)(m >> 32),
           __builtin_amdgcn_mbcnt_lo((uint)m, 0u));
}

// ---------------------------------------------------------------------------
// K1 (R13-proven): H = relu(X @ Wa + ba) -> bf16. 128x128 tile, 4 waves 2x2,
// wave = 64x64 = 4x4 frags of 16x16x32. A staged from fp32 X; B by inline
// transpose+convert of Wa. LDS XOR swizzle on 16B granules (write AND read).
// ---------------------------------------------------------------------------
__global__ __launch_bounds__(256) void gemm_k1_k(
    const float* __restrict__ X, const float* __restrict__ Wa,
    const float* __restrict__ ba, ushort* __restrict__ H)
{
    __shared__ ushort Asm[128 * 128];
    __shared__ ushort Bsm[128 * 128];
    const int tid = threadIdx.x, l = tid & 63, w = tid >> 6;
    const int wm = (w >> 1) * 64, wn = (w & 1) * 64;
    const size_t row0 = (size_t)blockIdx.x * 128;

#pragma unroll
    for (int j = 0; j < 8; ++j) {
        int gid = (j << 8) + tid;              // 16B granule id
        int r = gid >> 4, g = gid & 15;
        const float* s = X + (row0 + r) * 128 + g * 8;
        short8 pk;
#pragma unroll
        for (int e = 0; e < 8; ++e) pk[e] = (short)f2bf(s[e]);
        *(short8*)&Asm[r * 128 + ((g ^ (r & 7)) << 3)] = pk;
    }
    {
        int c = tid >> 1;                      // output col d
        int g0 = (tid & 1) * 8;                // granule half
#pragma unroll
        for (int g = g0; g < g0 + 8; ++g) {
            short8 pk;
#pragma unroll
            for (int e = 0; e < 8; ++e)
                pk[e] = (short)f2bf(Wa[(size_t)(g * 8 + e) * 128 + c]);
            *(short8*)&Bsm[c * 128 + ((g ^ (c & 7)) << 3)] = pk;
        }
    }
    __syncthreads();

    f32x4 acc[4][4] = {};
#pragma unroll
    for (int ks = 0; ks < 4; ++ks) {
        int gg = (ks << 2) + (l >> 4);
        short8 af[4], bfr[4];
#pragma unroll
        for (int m = 0; m < 4; ++m) {
            int r = wm + m * 16 + (l & 15);
            af[m] = *(const short8*)&Asm[r * 128 + ((gg ^ (r & 7)) << 3)];
        }
#pragma unroll
        for (int n = 0; n < 4; ++n) {
            int c = wn + n * 16 + (l & 15);
            bfr[n] = *(const short8*)&Bsm[c * 128 + ((gg ^ (c & 7)) << 3)];
        }
#pragma unroll
        for (int m = 0; m < 4; ++m)
#pragma unroll
            for (int n = 0; n < 4; ++n)
                acc[m][n] = __builtin_amdgcn_mfma_f32_16x16x32_bf16(
                    af[m], bfr[n], acc[m][n], 0, 0, 0);
    }

    float bcol[4];
#pragma unroll
    for (int n = 0; n < 4; ++n) bcol[n] = ba[wn + n * 16 + (l & 15)];
#pragma unroll
    for (int m = 0; m < 4; ++m) {
        int rbase = wm + m * 16 + ((l >> 4) << 2);   // C/D: row = 4*(l>>4)+reg
#pragma unroll
        for (int n = 0; n < 4; ++n) {
            int col = wn + n * 16 + (l & 15);        // C/D: col = l&15
#pragma unroll
            for (int r = 0; r < 4; ++r)
                H[(row0 + rbase + r) * 128 + col] =
                    f2bf(fmaxf(acc[m][n][r] + bcol[n], 0.f));
        }
    }
}

// ---------------------------------------------------------------------------
// K2 (R13-proven; plain cacheable A loads): one wave per node. Batch-affine
// XCD mapping (batch = {xcd, xcd+8}) keeps each batch's 512 KB H slice in
// one L2. Rank-based ballot scan -> first min(deg,S) ascending indices
// (== lax.top_k of binary mask) -> LDS; pad to 32 with idxs[0] (max
// idempotent; pad loads hit L1, same address); 32 gathers all in flight.
// acc init = relu(ba) (= padded slot value). Blocks >= 8192: Wct prep.
// ---------------------------------------------------------------------------
__global__ __launch_bounds__(256) void agg_k(
    const float* __restrict__ A,        // [32768][2048]
    const uint*  __restrict__ Hu,       // [32768][64] (bf16 pairs)
    const float* __restrict__ ba,
    uint* __restrict__ aggu,            // [32768][64] (bf16 pairs)
    const int* __restrict__ nsp,
    const float* __restrict__ Wc,       // for folded prep
    ushort* __restrict__ Wct)
{
    if (blockIdx.x >= 8192) {           // folded Wct prep: 128 blocks
        int j = (blockIdx.x - 8192) * 256 + threadIdx.x;   // < 32768
        int d = j >> 8, k = j & 255;
        Wct[j] = f2bf(Wc[k * 128 + d]);
        return;
    }

    __shared__ int idxs[4][32];
    const int l = threadIdx.x & 63;
    const int w = threadIdx.x >> 6;
    const int bid   = blockIdx.x;
    const int xcd   = bid & 7;
    const int grp   = bid >> 3;                  // 0..1023
    const int batch = ((grp >> 9) << 3) + xcd;   // {xcd, xcd+8}
    const int node  = (batch << 11) + ((grp & 511) << 2) + w;
    int S = nsp[0]; if (S > 32) S = 32;

    const fvec4* rowp = (const fvec4*)(A + (size_t)node * 2048);
    fvec4 v[8];
#pragma unroll
    for (int c = 0; c < 8; ++c)
        v[c] = rowp[c * 64 + l];                 // cacheable (was NT in R13)

    int base = 0;
#pragma unroll
    for (int c = 0; c < 8; ++c) {
        if (base < S) {                              // wave-uniform skip
            unsigned long long m0 = __ballot(v[c][0] != 0.f);
            unsigned long long m1 = __ballot(v[c][1] != 0.f);
            unsigned long long m2 = __ballot(v[c][2] != 0.f);
            unsigned long long m3 = __ballot(v[c][3] != 0.f);
            int below = mbcnt64(m0) + mbcnt64(m1) + mbcnt64(m2) + mbcnt64(m3);
            int o0 = (int)((m0 >> l) & 1), o1 = (int)((m1 >> l) & 1);
            int o2 = (int)((m2 >> l) & 1), o3 = (int)((m3 >> l) & 1);
            int r0 = base + below;
            int r1 = r0 + o0, r2 = r1 + o1, r3 = r2 + o2;
            int e = (c << 8) + (l << 2);
            if (o0 && r0 < S) idxs[w][r0] = e;
            if (o1 && r1 < S) idxs[w][r1] = e + 1;
            if (o2 && r2 < S) idxs[w][r2] = e + 2;
            if (o3 && r3 < S) idxs[w][r3] = e + 3;
            base += __popcll(m0) + __popcll(m1) + __popcll(m2) + __popcll(m3);
        }
    }
    int found = base < S ? base : S;

    float i0 = fmaxf(ba[2 * l], 0.f), i1 = fmaxf(ba[2 * l + 1], 0.f);
    float r0f = i0, r1f = i1;
    if (found > 0) {
        int fill = idxs[w][0];                       // broadcast read
        if (l < 32)                                  // pad list to 32
            idxs[w][l] = (l < found) ? idxs[w][l] : fill;

        const uint* HB = Hu + ((size_t)batch << 17); // batch*2048*64
        uint h[32];
#pragma unroll
        for (int q = 0; q < 32; ++q)                 // all 32 in flight
            h[q] = HB[(size_t)idxs[w][q] * 64 + l];

        float a0[8], a1[8];
#pragma unroll
        for (int q = 0; q < 8; ++q) { a0[q] = i0; a1[q] = i1; }
#pragma unroll
        for (int q = 0; q < 32; ++q) {
            a0[q & 7] = fmaxf(a0[q & 7], bflo(h[q]));
            a1[q & 7] = fmaxf(a1[q & 7], bfhi(h[q]));
        }
#pragma unroll
        for (int q = 0; q < 4; ++q) {
            a0[q] = fmaxf(a0[q], a0[q + 4]);
            a1[q] = fmaxf(a1[q], a1[q + 4]);
        }
        r0f = fmaxf(fmaxf(a0[0], a0[1]), fmaxf(a0[2], a0[3]));
        r1f = fmaxf(fmaxf(a1[0], a1[1]), fmaxf(a1[2], a1[3]));
    }
    aggu[(size_t)node * 64 + l] = (uint)f2bf(r0f) | ((uint)f2bf(r1f) << 16);
}

// ---------------------------------------------------------------------------
// K3 (R13-proven): out = relu([X|agg] @ Wc + bc) + per-block sumsq partials.
// ---------------------------------------------------------------------------
__global__ __launch_bounds__(256) void gemm_k3_k(
    const float* __restrict__ X, const ushort* __restrict__ agg,
    const ushort* __restrict__ Wct, const float* __restrict__ bc,
    float* __restrict__ out, float* __restrict__ partials)
{
    __shared__ ushort Asm[128 * 128];
    __shared__ ushort Bsm[128 * 128];
    __shared__ float wred[4];
    const int tid = threadIdx.x, l = tid & 63, w = tid >> 6;
    const int wm = (w >> 1) * 64, wn = (w & 1) * 64;
    const size_t row0 = (size_t)blockIdx.x * 128;

    f32x4 acc[4][4] = {};
    for (int t = 0; t < 2; ++t) {
        __syncthreads();
        if (t == 0) {
#pragma unroll
            for (int j = 0; j < 8; ++j) {
                int gid = (j << 8) + tid;
                int r = gid >> 4, g = gid & 15;
                const float* s = X + (row0 + r) * 128 + g * 8;
                short8 pk;
#pragma unroll
                for (int e = 0; e < 8; ++e) pk[e] = (short)f2bf(s[e]);
                *(short8*)&Asm[r * 128 + ((g ^ (r & 7)) << 3)] = pk;
            }
        } else {
#pragma unroll
            for (int j = 0; j < 8; ++j) {
                int gid = (j << 8) + tid;
                int r = gid >> 4, g = gid & 15;
                short8 v = *(const short8*)(agg + (row0 + r) * 128 + g * 8);
                *(short8*)&Asm[r * 128 + ((g ^ (r & 7)) << 3)] = v;
            }
        }
#pragma unroll
        for (int j = 0; j < 8; ++j) {
            int gid = (j << 8) + tid;
            int r = gid >> 4, g = gid & 15;
            short8 v = *(const short8*)(Wct + (size_t)r * 256 + (t << 7) + g * 8);
            *(short8*)&Bsm[r * 128 + ((g ^ (r & 7)) << 3)] = v;
        }
        __syncthreads();
#pragma unroll
        for (int ks = 0; ks < 4; ++ks) {
            int gg = (ks << 2) + (l >> 4);
            short8 af[4], bfr[4];
#pragma unroll
            for (int m = 0; m < 4; ++m) {
                int r = wm + m * 16 + (l & 15);
                af[m] = *(const short8*)&Asm[r * 128 + ((gg ^ (r & 7)) << 3)];
            }
#pragma unroll
            for (int n = 0; n < 4; ++n) {
                int c = wn + n * 16 + (l & 15);
                bfr[n] = *(const short8*)&Bsm[c * 128 + ((gg ^ (c & 7)) << 3)];
            }
#pragma unroll
            for (int m = 0; m < 4; ++m)
#pragma unroll
                for (int n = 0; n < 4; ++n)
                    acc[m][n] = __builtin_amdgcn_mfma_f32_16x16x32_bf16(
                        af[m], bfr[n], acc[m][n], 0, 0, 0);
        }
    }

    float bcol[4];
#pragma unroll
    for (int n = 0; n < 4; ++n) bcol[n] = bc[wn + n * 16 + (l & 15)];
    float lsum = 0.f;
#pragma unroll
    for (int m = 0; m < 4; ++m) {
        int rbase = wm + m * 16 + ((l >> 4) << 2);   // C/D: row = 4*(l>>4)+reg
#pragma unroll
        for (int n = 0; n < 4; ++n) {
            int col = wn + n * 16 + (l & 15);        // C/D: col = l&15
#pragma unroll
            for (int r = 0; r < 4; ++r) {
                float v = fmaxf(acc[m][n][r] + bcol[n], 0.f);
                out[(row0 + rbase + r) * 128 + col] = v;
                lsum += v * v;
            }
        }
    }
#pragma unroll
    for (int off = 32; off > 0; off >>= 1) lsum += __shfl_down(lsum, off);
    if (l == 0) wred[w] = lsum;
    __syncthreads();
    if (tid == 0)
        partials[blockIdx.x] = wred[0] + wred[1] + wred[2] + wred[3];
}

// ---------------------------------------------------------------------------
// K5 (R13-proven): per-batch frobenius normalize in place; each block
// deterministically reduces its batch's 16 partials. div_no_nan.
// ---------------------------------------------------------------------------
__global__ __launch_bounds__(256) void scale_k(
    float* __restrict__ out, const float* __restrict__ partials)
{
    const int blk = blockIdx.x;
    const int b = blk >> 6;                          // 64 blocks per batch
    float s = 0.f;
#pragma unroll
    for (int i = 0; i < 16; ++i) s += partials[b * 16 + i];
    float norm = sqrtf(s);
    float sc = (norm > 0.f) ? (1.f / norm) : 0.f;
    fvec4* o4 = (fvec4*)out;
    int i0 = blk * 1024 + threadIdx.x;
#pragma unroll
    for (int k = 0; k < 4; ++k) {
        fvec4 v = o4[i0 + k * 256];
        o4[i0 + k * 256] = v * sc;
    }
}

extern "C" void kernel_launch(void* const* d_in, const int* in_sizes, int n_in,
                              void* d_out, int out_size, void* d_ws, size_t ws_size,
                              hipStream_t stream) {
    const float* A  = (const float*)d_in[0];
    const float* X  = (const float*)d_in[1];
    const float* Wa = (const float*)d_in[2];
    const float* ba = (const float*)d_in[3];
    const float* Wc = (const float*)d_in[4];
    const float* bc = (const float*)d_in[5];
    const int*  nsp = (const int*)d_in[6];

    float* out = (float*)d_out;
    char* ws = (char*)d_ws;
    ushort* H        = (ushort*)ws;                              // 8 MB
    ushort* agg      = (ushort*)(ws + (8u << 20));               // 8 MB
    ushort* Wct      = (ushort*)(ws + (16u << 20));              // 64 KB
    float*  partials = (float*) (ws + (16u << 20) + 65536);      // 1 KB

    // K1: H = relu(X @ Wa + ba), inline Wa transpose (no prep dispatch)
    gemm_k1_k<<<256, 256, 0, stream>>>(X, Wa, ba, H);
    // K2: agg = max over first-S neighbors (+ folded Wct prep blocks >= 8192)
    agg_k<<<8192 + 128, 256, 0, stream>>>(A, (const uint*)H, ba, (uint*)agg,
                                          nsp, Wc, Wct);
    // K3: out = relu([X|agg] @ Wc + bc) + partial sumsq
    gemm_k3_k<<<256, 256, 0, stream>>>(X, agg, Wct, bc, out, partials);
    // K5: normalize
    scale_k<<<1024, 256, 0, stream>>>(out, partials);
}

// Round 16
// 81.307 us; speedup vs baseline: 1.0465x; 1.0465x over previous
//
#include <hip/hip_runtime.h>

// B=16, N=2048, C=128, S=25, D_AGG=128, D_OUT=128
// in: A[16,2048,2048] f32, X[16,2048,128] f32, Wa[128,128] f32, ba[128] f32,
//     Wc[256,128] f32, bc[128] f32, n_samples i32
// out: [16,2048,128] f32
//
// Pipeline (R13 structure; K2 now 1-wave-per-block for per-wave block
// retirement / denser turnover. NT A-loads restored per R15 A/B):
//   K1     : H = relu(X @ Wa + ba) -> bf16 (MFMA; inline Wa transpose)
//   K2     : one 64-thread block per node: NT row load -> ballot-rank scan
//            (mbcnt) -> 32-wide batched gather-max. Batch-affine XCD map.
//            Blocks >= 32768: Wct prep (512 x 64).
//   K3     : out = relu([X|agg] @ Wc + bc) -> f32 + partial sumsq (MFMA)
//   K5     : out *= 1/frobnorm per batch (div_no_nan)
//
// ws: H 8MB @0, agg 8MB @8M, Wct 64K @16M, partials 1K @16M+64K

typedef __attribute__((ext_vector_type(8))) short short8;   // bf16x8 raw bits
typedef __attribute__((ext_vector_type(4))) float f32x4;
typedef __attribute__((ext_vector_type(4))) float fvec4;
typedef unsigned int uint;
typedef unsigned short ushort;

__device__ __forceinline__ ushort f2bf(float x) {           // RNE f32->bf16
    uint u = __builtin_bit_cast(uint, x);
    u += 0x7FFFu + ((u >> 16) & 1u);
    return (ushort)(u >> 16);
}
__device__ __forceinline__ float bflo(uint h) { uint v = h << 16;         return __builtin_bit_cast(float, v); }
__device__ __forceinline__ float bfhi(uint h) { uint v = h & 0xFFFF0000u; return __builtin_bit_cast(float, v); }
// popcount(mask & lanemask_lt) in 2 VALU ops (R9/R11/R13-proven)
__device__ __forceinline__ int mbcnt64(unsigned long long m) {
    return __builtin_amdgcn_mbcnt_hi((uint)(m >> 32),
           __builtin_amdgcn_mbcnt_lo((uint)m, 0u));
}

// ---------------------------------------------------------------------------
// K1 (R13-proven): H = relu(X @ Wa + ba) -> bf16. 128x128 tile, 4 waves 2x2,
// wave = 64x64 = 4x4 frags of 16x16x32. A staged from fp32 X; B by inline
// transpose+convert of Wa. LDS XOR swizzle on 16B granules (write AND read).
// ---------------------------------------------------------------------------
__global__ __launch_bounds__(256) void gemm_k1_k(
    const float* __restrict__ X, const float* __restrict__ Wa,
    const float* __restrict__ ba, ushort* __restrict__ H)
{
    __shared__ ushort Asm[128 * 128];
    __shared__ ushort Bsm[128 * 128];
    const int tid = threadIdx.x, l = tid & 63, w = tid >> 6;
    const int wm = (w >> 1) * 64, wn = (w & 1) * 64;
    const size_t row0 = (size_t)blockIdx.x * 128;

#pragma unroll
    for (int j = 0; j < 8; ++j) {
        int gid = (j << 8) + tid;              // 16B granule id
        int r = gid >> 4, g = gid & 15;
        const float* s = X + (row0 + r) * 128 + g * 8;
        short8 pk;
#pragma unroll
        for (int e = 0; e < 8; ++e) pk[e] = (short)f2bf(s[e]);
        *(short8*)&Asm[r * 128 + ((g ^ (r & 7)) << 3)] = pk;
    }
    {
        int c = tid >> 1;                      // output col d
        int g0 = (tid & 1) * 8;                // granule half
#pragma unroll
        for (int g = g0; g < g0 + 8; ++g) {
            short8 pk;
#pragma unroll
            for (int e = 0; e < 8; ++e)
                pk[e] = (short)f2bf(Wa[(size_t)(g * 8 + e) * 128 + c]);
            *(short8*)&Bsm[c * 128 + ((g ^ (c & 7)) << 3)] = pk;
        }
    }
    __syncthreads();

    f32x4 acc[4][4] = {};
#pragma unroll
    for (int ks = 0; ks < 4; ++ks) {
        int gg = (ks << 2) + (l >> 4);
        short8 af[4], bfr[4];
#pragma unroll
        for (int m = 0; m < 4; ++m) {
            int r = wm + m * 16 + (l & 15);
            af[m] = *(const short8*)&Asm[r * 128 + ((gg ^ (r & 7)) << 3)];
        }
#pragma unroll
        for (int n = 0; n < 4; ++n) {
            int c = wn + n * 16 + (l & 15);
            bfr[n] = *(const short8*)&Bsm[c * 128 + ((gg ^ (c & 7)) << 3)];
        }
#pragma unroll
        for (int m = 0; m < 4; ++m)
#pragma unroll
            for (int n = 0; n < 4; ++n)
                acc[m][n] = __builtin_amdgcn_mfma_f32_16x16x32_bf16(
                    af[m], bfr[n], acc[m][n], 0, 0, 0);
    }

    float bcol[4];
#pragma unroll
    for (int n = 0; n < 4; ++n) bcol[n] = ba[wn + n * 16 + (l & 15)];
#pragma unroll
    for (int m = 0; m < 4; ++m) {
        int rbase = wm + m * 16 + ((l >> 4) << 2);   // C/D: row = 4*(l>>4)+reg
#pragma unroll
        for (int n = 0; n < 4; ++n) {
            int col = wn + n * 16 + (l & 15);        // C/D: col = l&15
#pragma unroll
            for (int r = 0; r < 4; ++r)
                H[(row0 + rbase + r) * 128 + col] =
                    f2bf(fmaxf(acc[m][n][r] + bcol[n], 0.f));
        }
    }
}

// ---------------------------------------------------------------------------
// K2 (R13 data path; 1-wave blocks): one 64-thread block per node. Block
// retires when ITS wave finishes -> denser block turnover than 4-wave
// blocks (slowest-wave retirement). Batch-affine XCD mapping (batch =
// {xcd, xcd+8}). NT A loads (R15 A/B: NT beats cacheable by 3.5us).
// Rank-based ballot scan -> first min(deg,S) ascending indices -> LDS;
// pad to 32 (idempotent max); 32 gathers in flight. acc init = relu(ba).
// Blocks >= 32768: Wct prep (512 blocks x 64 threads).
// ---------------------------------------------------------------------------
__global__ __launch_bounds__(64) void agg_k(
    const float* __restrict__ A,        // [32768][2048]
    const uint*  __restrict__ Hu,       // [32768][64] (bf16 pairs)
    const float* __restrict__ ba,
    uint* __restrict__ aggu,            // [32768][64] (bf16 pairs)
    const int* __restrict__ nsp,
    const float* __restrict__ Wc,       // for folded prep
    ushort* __restrict__ Wct)
{
    if (blockIdx.x >= 32768) {          // folded Wct prep: 512 blocks
        int j = (blockIdx.x - 32768) * 64 + threadIdx.x;   // < 32768
        int d = j >> 8, k = j & 255;
        Wct[j] = f2bf(Wc[k * 128 + d]);
        return;
    }

    __shared__ int idxs[32];
    const int l = threadIdx.x;                   // 0..63, one wave
    const int bid   = blockIdx.x;
    const int xcd   = bid & 7;
    const int grp   = bid >> 3;                  // 0..4095
    const int batch = ((grp >> 11) << 3) + xcd;  // {xcd, xcd+8}
    const int node  = (batch << 11) + (grp & 2047);
    int S = nsp[0]; if (S > 32) S = 32;

    const fvec4* rowp = (const fvec4*)(A + (size_t)node * 2048);
    fvec4 v[8];
#pragma unroll
    for (int c = 0; c < 8; ++c)
        v[c] = __builtin_nontemporal_load(rowp + c * 64 + l);

    int base = 0;
#pragma unroll
    for (int c = 0; c < 8; ++c) {
        if (base < S) {                              // wave-uniform skip
            unsigned long long m0 = __ballot(v[c][0] != 0.f);
            unsigned long long m1 = __ballot(v[c][1] != 0.f);
            unsigned long long m2 = __ballot(v[c][2] != 0.f);
            unsigned long long m3 = __ballot(v[c][3] != 0.f);
            int below = mbcnt64(m0) + mbcnt64(m1) + mbcnt64(m2) + mbcnt64(m3);
            int o0 = (int)((m0 >> l) & 1), o1 = (int)((m1 >> l) & 1);
            int o2 = (int)((m2 >> l) & 1), o3 = (int)((m3 >> l) & 1);
            int r0 = base + below;
            int r1 = r0 + o0, r2 = r1 + o1, r3 = r2 + o2;
            int e = (c << 8) + (l << 2);
            if (o0 && r0 < S) idxs[r0] = e;
            if (o1 && r1 < S) idxs[r1] = e + 1;
            if (o2 && r2 < S) idxs[r2] = e + 2;
            if (o3 && r3 < S) idxs[r3] = e + 3;
            base += __popcll(m0) + __popcll(m1) + __popcll(m2) + __popcll(m3);
        }
    }
    int found = base < S ? base : S;

    float i0 = fmaxf(ba[2 * l], 0.f), i1 = fmaxf(ba[2 * l + 1], 0.f);
    float r0f = i0, r1f = i1;
    if (found > 0) {
        int fill = idxs[0];                          // broadcast read
        if (l < 32)                                  // pad list to 32
            idxs[l] = (l < found) ? idxs[l] : fill;

        const uint* HB = Hu + ((size_t)batch << 17); // batch*2048*64
        uint h[32];
#pragma unroll
        for (int q = 0; q < 32; ++q)                 // all 32 in flight
            h[q] = HB[(size_t)idxs[q] * 64 + l];

        float a0[8], a1[8];
#pragma unroll
        for (int q = 0; q < 8; ++q) { a0[q] = i0; a1[q] = i1; }
#pragma unroll
        for (int q = 0; q < 32; ++q) {
            a0[q & 7] = fmaxf(a0[q & 7], bflo(h[q]));
            a1[q & 7] = fmaxf(a1[q & 7], bfhi(h[q]));
        }
#pragma unroll
        for (int q = 0; q < 4; ++q) {
            a0[q] = fmaxf(a0[q], a0[q + 4]);
            a1[q] = fmaxf(a1[q], a1[q + 4]);
        }
        r0f = fmaxf(fmaxf(a0[0], a0[1]), fmaxf(a0[2], a0[3]));
        r1f = fmaxf(fmaxf(a1[0], a1[1]), fmaxf(a1[2], a1[3]));
    }
    aggu[(size_t)node * 64 + l] = (uint)f2bf(r0f) | ((uint)f2bf(r1f) << 16);
}

// ---------------------------------------------------------------------------
// K3 (R13-proven): out = relu([X|agg] @ Wc + bc) + per-block sumsq partials.
// ---------------------------------------------------------------------------
__global__ __launch_bounds__(256) void gemm_k3_k(
    const float* __restrict__ X, const ushort* __restrict__ agg,
    const ushort* __restrict__ Wct, const float* __restrict__ bc,
    float* __restrict__ out, float* __restrict__ partials)
{
    __shared__ ushort Asm[128 * 128];
    __shared__ ushort Bsm[128 * 128];
    __shared__ float wred[4];
    const int tid = threadIdx.x, l = tid & 63, w = tid >> 6;
    const int wm = (w >> 1) * 64, wn = (w & 1) * 64;
    const size_t row0 = (size_t)blockIdx.x * 128;

    f32x4 acc[4][4] = {};
    for (int t = 0; t < 2; ++t) {
        __syncthreads();
        if (t == 0) {
#pragma unroll
            for (int j = 0; j < 8; ++j) {
                int gid = (j << 8) + tid;
                int r = gid >> 4, g = gid & 15;
                const float* s = X + (row0 + r) * 128 + g * 8;
                short8 pk;
#pragma unroll
                for (int e = 0; e < 8; ++e) pk[e] = (short)f2bf(s[e]);
                *(short8*)&Asm[r * 128 + ((g ^ (r & 7)) << 3)] = pk;
            }
        } else {
#pragma unroll
            for (int j = 0; j < 8; ++j) {
                int gid = (j << 8) + tid;
                int r = gid >> 4, g = gid & 15;
                short8 v = *(const short8*)(agg + (row0 + r) * 128 + g * 8);
                *(short8*)&Asm[r * 128 + ((g ^ (r & 7)) << 3)] = v;
            }
        }
#pragma unroll
        for (int j = 0; j < 8; ++j) {
            int gid = (j << 8) + tid;
            int r = gid >> 4, g = gid & 15;
            short8 v = *(const short8*)(Wct + (size_t)r * 256 + (t << 7) + g * 8);
            *(short8*)&Bsm[r * 128 + ((g ^ (r & 7)) << 3)] = v;
        }
        __syncthreads();
#pragma unroll
        for (int ks = 0; ks < 4; ++ks) {
            int gg = (ks << 2) + (l >> 4);
            short8 af[4], bfr[4];
#pragma unroll
            for (int m = 0; m < 4; ++m) {
                int r = wm + m * 16 + (l & 15);
                af[m] = *(const short8*)&Asm[r * 128 + ((gg ^ (r & 7)) << 3)];
            }
#pragma unroll
            for (int n = 0; n < 4; ++n) {
                int c = wn + n * 16 + (l & 15);
                bfr[n] = *(const short8*)&Bsm[c * 128 + ((gg ^ (c & 7)) << 3)];
            }
#pragma unroll
            for (int m = 0; m < 4; ++m)
#pragma unroll
                for (int n = 0; n < 4; ++n)
                    acc[m][n] = __builtin_amdgcn_mfma_f32_16x16x32_bf16(
                        af[m], bfr[n], acc[m][n], 0, 0, 0);
        }
    }

    float bcol[4];
#pragma unroll
    for (int n = 0; n < 4; ++n) bcol[n] = bc[wn + n * 16 + (l & 15)];
    float lsum = 0.f;
#pragma unroll
    for (int m = 0; m < 4; ++m) {
        int rbase = wm + m * 16 + ((l >> 4) << 2);   // C/D: row = 4*(l>>4)+reg
#pragma unroll
        for (int n = 0; n < 4; ++n) {
            int col = wn + n * 16 + (l & 15);        // C/D: col = l&15
#pragma unroll
            for (int r = 0; r < 4; ++r) {
                float v = fmaxf(acc[m][n][r] + bcol[n], 0.f);
                out[(row0 + rbase + r) * 128 + col] = v;
                lsum += v * v;
            }
        }
    }
#pragma unroll
    for (int off = 32; off > 0; off >>= 1) lsum += __shfl_down(lsum, off);
    if (l == 0) wred[w] = lsum;
    __syncthreads();
    if (tid == 0)
        partials[blockIdx.x] = wred[0] + wred[1] + wred[2] + wred[3];
}

// ---------------------------------------------------------------------------
// K5 (R13-proven): per-batch frobenius normalize in place; each block
// deterministically reduces its batch's 16 partials. div_no_nan.
// ---------------------------------------------------------------------------
__global__ __launch_bounds__(256) void scale_k(
    float* __restrict__ out, const float* __restrict__ partials)
{
    const int blk = blockIdx.x;
    const int b = blk >> 6;                          // 64 blocks per batch
    float s = 0.f;
#pragma unroll
    for (int i = 0; i < 16; ++i) s += partials[b * 16 + i];
    float norm = sqrtf(s);
    float sc = (norm > 0.f) ? (1.f / norm) : 0.f;
    fvec4* o4 = (fvec4*)out;
    int i0 = blk * 1024 + threadIdx.x;
#pragma unroll
    for (int k = 0; k < 4; ++k) {
        fvec4 v = o4[i0 + k * 256];
        o4[i0 + k * 256] = v * sc;
    }
}

extern "C" void kernel_launch(void* const* d_in, const int* in_sizes, int n_in,
                              void* d_out, int out_size, void* d_ws, size_t ws_size,
                              hipStream_t stream) {
    const float* A  = (const float*)d_in[0];
    const float* X  = (const float*)d_in[1];
    const float* Wa = (const float*)d_in[2];
    const float* ba = (const float*)d_in[3];
    const float* Wc = (const float*)d_in[4];
    const float* bc = (const float*)d_in[5];
    const int*  nsp = (const int*)d_in[6];

    float* out = (float*)d_out;
    char* ws = (char*)d_ws;
    ushort* H        = (ushort*)ws;                              // 8 MB
    ushort* agg      = (ushort*)(ws + (8u << 20));               // 8 MB
    ushort* Wct      = (ushort*)(ws + (16u << 20));              // 64 KB
    float*  partials = (float*) (ws + (16u << 20) + 65536);      // 1 KB

    // K1: H = relu(X @ Wa + ba), inline Wa transpose (no prep dispatch)
    gemm_k1_k<<<256, 256, 0, stream>>>(X, Wa, ba, H);
    // K2: 1-wave blocks, one per node (+ folded Wct prep blocks >= 32768)
    agg_k<<<32768 + 512, 64, 0, stream>>>(A, (const uint*)H, ba, (uint*)agg,
                                          nsp, Wc, Wct);
    // K3: out = relu([X|agg] @ Wc + bc) + partial sumsq
    gemm_k3_k<<<256, 256, 0, stream>>>(X, agg, Wct, bc, out, partials);
    // K5: normalize
    scale_k<<<1024, 256, 0, stream>>>(out, partials);
}